// Round 2
// baseline (121.944 us; speedup 1.0000x reference)
//
#include <hip/hip_runtime.h>
#include <cstdint>

#define NB 2
#define LL 384
#define DIN 256
#define DE 128
#define NH 8
#define DH 32
#define HD 256          // NH*DH
#define SCALE 0.17677669529663687f

typedef __attribute__((ext_vector_type(8))) short bf16x8;
typedef __attribute__((ext_vector_type(4))) float f32x4;

static __device__ __forceinline__ unsigned short f2bf(float f) {
    uint32_t u = __builtin_bit_cast(uint32_t, f);
    u += 0x7FFF + ((u >> 16) & 1);          // RNE
    return (unsigned short)(u >> 16);
}
static __device__ __forceinline__ float bf2f(unsigned short u) {
    return __builtin_bit_cast(float, (uint32_t)u << 16);
}
static __device__ __forceinline__ float getf4(const float4& v, int k) {
    return k == 0 ? v.x : k == 1 ? v.y : k == 2 ? v.z : v.w;
}
static __device__ __forceinline__ bf16x8 pack8(const float4& a, const float4& b) {
    bf16x8 p;
    p[0]=(short)f2bf(a.x); p[1]=(short)f2bf(a.y); p[2]=(short)f2bf(a.z); p[3]=(short)f2bf(a.w);
    p[4]=(short)f2bf(b.x); p[5]=(short)f2bf(b.y); p[6]=(short)f2bf(b.z); p[7]=(short)f2bf(b.w);
    return p;
}

// ---------------- prep_we: We^T -> bf16 (HD x DE, n-major) ----------------
__global__ __launch_bounds__(128) void prep_we(const float* __restrict__ We,
                                               unsigned short* __restrict__ WeT) {
    const int n = blockIdx.x;    // 0..255
    const int k = threadIdx.x;   // 0..127
    WeT[n * DE + k] = f2bf(We[(size_t)k * HD + n]);
}

// ---------------- proj: q/k -> bf16, v/u -> fp32 ----------------
__global__ __launch_bounds__(256) void proj_kernel(
    const float* __restrict__ node,
    const float* __restrict__ Wq, const float* __restrict__ bq,
    const float* __restrict__ Wk, const float* __restrict__ bk,
    const float* __restrict__ Wv, const float* __restrict__ bv,
    const float* __restrict__ Wu, const float* __restrict__ bu,
    unsigned short* __restrict__ qb16, unsigned short* __restrict__ kb16,
    float* __restrict__ vb, float* __restrict__ ub)
{
    __shared__ __align__(16) float rows[4][DIN];
    const int t  = threadIdx.x;
    const int r0 = blockIdx.x * 4;

    #pragma unroll
    for (int r = 0; r < 4; ++r)
        rows[r][t] = node[(size_t)(r0 + r) * DIN + t];
    __syncthreads();

    float aq[4], ak[4], av[4], au[4];
    {
        const float vq = bq[t], vk = bk[t], vv = bv[t], vu = bu[t];
        #pragma unroll
        for (int r = 0; r < 4; ++r) { aq[r] = vq; ak[r] = vk; av[r] = vv; au[r] = vu; }
    }

    for (int f4 = 0; f4 < DIN / 4; ++f4) {
        float4 xv[4];
        #pragma unroll
        for (int r = 0; r < 4; ++r)
            xv[r] = *(const float4*)&rows[r][f4 * 4];
        #pragma unroll
        for (int k = 0; k < 4; ++k) {
            const int f = f4 * 4 + k;
            const float wq = Wq[(size_t)f * HD + t];
            const float wk = Wk[(size_t)f * HD + t];
            const float wv = Wv[(size_t)f * HD + t];
            const float wu = Wu[(size_t)f * HD + t];
            #pragma unroll
            for (int r = 0; r < 4; ++r) {
                const float x = getf4(xv[r], k);
                aq[r] += x * wq; ak[r] += x * wk; av[r] += x * wv; au[r] += x * wu;
            }
        }
    }

    #pragma unroll
    for (int r = 0; r < 4; ++r) {
        const size_t o = (size_t)(r0 + r) * HD + t;
        qb16[o] = f2bf(aq[r]); kb16[o] = f2bf(ak[r]);
        vb[o] = av[r]; ub[o] = au[r];
    }
}

// ---------------- vt: v (fp32, j-major) -> vT (bf16, col-major) ----------------
__global__ __launch_bounds__(256) void vt_kernel(const float* __restrict__ vb,
                                                 unsigned short* __restrict__ vT) {
    __shared__ float tile[64][65];
    int blk = blockIdx.x;
    const int b  = blk / 24; blk %= 24;
    const int jt = blk / 4;
    const int ct = blk % 4;
    const int j0 = jt * 64, c0 = ct * 64;
    const int t  = threadIdx.x;
    const int c  = t & 63, j4 = t >> 6;
    #pragma unroll
    for (int rr = 0; rr < 16; ++rr) {
        const int j = j4 + 4 * rr;
        tile[j][c] = vb[(size_t)(b * LL + j0 + j) * HD + c0 + c];
    }
    __syncthreads();
    const int jj = t & 63, c4 = t >> 6;
    #pragma unroll
    for (int rr = 0; rr < 16; ++rr) {
        const int cc = c4 + 4 * rr;
        vT[(size_t)(b * HD + c0 + cc) * LL + j0 + jj] = f2bf(tile[jj][cc]);
    }
}

// ---------------- qk: lpre[b,h,i,j] = SCALE*(q.k) - 1e9*(1-mask) ----------------
__global__ __launch_bounds__(256) void qk_kernel(
    const unsigned short* __restrict__ qb16, const unsigned short* __restrict__ kb16,
    const float* __restrict__ mask, float* __restrict__ logit_pre)
{
    int idx = blockIdx.x;
    const int jt = idx % 6; idx /= 6;
    const int it = idx % 6; idx /= 6;
    const int h  = idx % NH;
    const int b  = idx / NH;
    const int t    = threadIdx.x;
    const int lane = t & 63;
    const int w    = t >> 6;
    const int lid  = lane & 15;
    const int g    = lane >> 4;
    const int i0 = it * 64 + w * 16;
    const int j0 = jt * 64;

    const bf16x8 afr = *(const bf16x8*)&qb16[(size_t)(b * LL + i0 + lid) * HD + h * DH + g * 8];
    f32x4 acc[4];
    #pragma unroll
    for (int jj = 0; jj < 4; ++jj) {
        const bf16x8 bfrg = *(const bf16x8*)&kb16[(size_t)(b * LL + j0 + jj * 16 + lid) * HD + h * DH + g * 8];
        acc[jj] = __builtin_amdgcn_mfma_f32_16x16x32_bf16(afr, bfrg, (f32x4){0.f,0.f,0.f,0.f}, 0, 0, 0);
    }
    #pragma unroll
    for (int jj = 0; jj < 4; ++jj) {
        #pragma unroll
        for (int r = 0; r < 4; ++r) {
            const int i = i0 + 4 * g + r;
            const int j = j0 + jj * 16 + lid;
            const float lg = SCALE * acc[jj][r]
                           + (1.0f - mask[(size_t)(b * LL + i) * LL + j]) * -1e9f;
            logit_pre[((size_t)(b * NH + h) * LL + i) * LL + j] = lg;
        }
    }
}

// ---------------- qwe: qWe[b,i,h,c] = SCALE * sum_d q[b,i,h*32+d]*We[c,h*32+d] ----------------
__global__ __launch_bounds__(256) void qwe_kernel(
    const unsigned short* __restrict__ qb16, const unsigned short* __restrict__ WeT,
    unsigned short* __restrict__ qWe)
{
    const int bi = blockIdx.x;
    const int t  = threadIdx.x;
    const int h  = t >> 5;
    const int c0 = (t & 31) * 4;

    float qv[32];
    const unsigned short* qp = &qb16[(size_t)bi * HD + h * DH];
    #pragma unroll
    for (int d = 0; d < 32; ++d) qv[d] = bf2f(qp[d]);

    float acc0 = 0.f, acc1 = 0.f, acc2 = 0.f, acc3 = 0.f;
    #pragma unroll
    for (int d = 0; d < 32; ++d) {
        const ushort4 wt = *(const ushort4*)&WeT[(size_t)(h * DH + d) * DE + c0];
        acc0 += qv[d] * bf2f(wt.x); acc1 += qv[d] * bf2f(wt.y);
        acc2 += qv[d] * bf2f(wt.z); acc3 += qv[d] * bf2f(wt.w);
    }
    unsigned short* o = &qWe[(size_t)bi * (NH * DE) + h * DE + c0];
    o[0] = f2bf(SCALE * acc0); o[1] = f2bf(SCALE * acc1);
    o[2] = f2bf(SCALE * acc2); o[3] = f2bf(SCALE * acc3);
}

// ---------------- elog: lpre[b,h,i,j] += (E_i @ qWe_i^T)[j,h] ----------------
// grid = NB*LL*3 blocks, 256 threads = 4 waves. Block: (b,i), j-tile of 128.
// Wave w covers j-local [32w, 32w+32). Straight-line, no LDS, no barriers.
__global__ __launch_bounds__(256) void elog_kernel(
    const float* __restrict__ edge,            // (B,L,L,DE)
    const unsigned short* __restrict__ qWe,    // (B,L,NH,DE) bf16, SCALE folded
    float* __restrict__ lpre)                  // += edge-logits (in place)
{
    int idx = blockIdx.x;
    const int jt = idx % 3; idx /= 3;
    const int bi = idx;
    const int b = bi / LL, ii = bi % LL;
    const int t = threadIdx.x, lane = t & 63, w = t >> 6;
    const int lid = lane & 15, g = lane >> 4;
    const int hq = lid & 7;
    const int j0 = jt * 128 + w * 32;

    // B-frags: B[k=c][n=h] = qWe[h][c]
    bf16x8 bfr[4];
    const unsigned short* qwp = &qWe[(size_t)bi * (NH * DE) + hq * DE];
    #pragma unroll
    for (int kt = 0; kt < 4; ++kt)
        bfr[kt] = *(const bf16x8*)&qwp[kt * 32 + g * 8];

    f32x4 acc[2];
    #pragma unroll
    for (int mt = 0; mt < 2; ++mt) {
        acc[mt] = (f32x4){0.f, 0.f, 0.f, 0.f};
        const float* ef = edge + ((size_t)bi * LL + j0 + mt * 16 + lid) * DE;
        #pragma unroll
        for (int kt = 0; kt < 4; ++kt) {
            const float4 x0 = *(const float4*)&ef[kt * 32 + g * 8];
            const float4 x1 = *(const float4*)&ef[kt * 32 + g * 8 + 4];
            acc[mt] = __builtin_amdgcn_mfma_f32_16x16x32_bf16(pack8(x0, x1), bfr[kt], acc[mt], 0, 0, 0);
        }
    }

    if (lid < 8) {
        float* lrow = lpre + ((size_t)(b * NH + hq) * LL + ii) * LL;
        #pragma unroll
        for (int mt = 0; mt < 2; ++mt) {
            float4* p4 = (float4*)&lrow[j0 + mt * 16 + 4 * g];
            float4 x = *p4;
            x.x += acc[mt][0]; x.y += acc[mt][1];
            x.z += acc[mt][2]; x.w += acc[mt][3];
            *p4 = x;
        }
    }
}

// ---------------- smax: attb[row,:] = softmax(lpre[row,:]) as bf16 ----------------
// grid = NB*NH*LL/4 blocks, 256 threads = 4 waves, one wave per row. No barriers.
__global__ __launch_bounds__(256) void smax_kernel(
    const float* __restrict__ lpre, unsigned short* __restrict__ attb)
{
    const int t = threadIdx.x, lane = t & 63, w = t >> 6;
    const int row = blockIdx.x * 4 + w;            // 0..6143 = (b*NH+h)*LL+i
    const float* lr = lpre + (size_t)row * LL;

    float2 x[3];
    #pragma unroll
    for (int k = 0; k < 3; ++k)
        x[k] = *(const float2*)&lr[2 * lane + 128 * k];

    float m = fmaxf(x[0].x, x[0].y);
    m = fmaxf(m, fmaxf(x[1].x, x[1].y));
    m = fmaxf(m, fmaxf(x[2].x, x[2].y));
    #pragma unroll
    for (int off = 1; off < 64; off <<= 1) m = fmaxf(m, __shfl_xor(m, off));

    float p[6], s = 0.f;
    #pragma unroll
    for (int k = 0; k < 3; ++k) {
        p[2 * k]     = __expf(x[k].x - m);
        p[2 * k + 1] = __expf(x[k].y - m);
        s += p[2 * k] + p[2 * k + 1];
    }
    #pragma unroll
    for (int off = 1; off < 64; off <<= 1) s += __shfl_xor(s, off);
    const float inv = 1.0f / s;

    unsigned int* ao = (unsigned int*)attb + (size_t)row * (LL / 2);
    #pragma unroll
    for (int k = 0; k < 3; ++k) {
        const unsigned int pk = ((unsigned int)f2bf(p[2 * k + 1] * inv) << 16)
                              |  (unsigned int)f2bf(p[2 * k] * inv);
        ao[lane + 64 * k] = pk;
    }
}

// ---------------- pvs: partial aE = p@E and av = p@v over a 128-j slice ----------------
// grid = NB*LL*3 blocks, 512 threads = 8 waves. Wave w: aE c-tile [16w,16w+16),
// av hd-tiles [32w,32w+32). No LDS, no barriers. E columns read as coalesced dwords.
__global__ __launch_bounds__(512, 4) void pvs_kernel(
    const float* __restrict__ edge,            // (B,L,L,DE)
    const unsigned short* __restrict__ attb,   // (B,NH,L,L) bf16 softmaxed
    const unsigned short* __restrict__ vT,     // (B,HD,L) bf16
    float* __restrict__ aEp,                   // (NB*LL, 3, NH, DE) partials
    float* __restrict__ avp)                   // (NB*LL, 3, HD) partials
{
    int idx = blockIdx.x;
    const int jt = idx % 3; idx /= 3;
    const int bi = idx;
    const int b = bi / LL, ii = bi % LL;
    const int t = threadIdx.x, lane = t & 63, w = t >> 6;
    const int lid = lane & 15, g = lane >> 4;
    const int h = lid & 7;
    const int j0 = jt * 128;

    // A-frags: A[m=h][k=j] = att[h][j0+k]
    bf16x8 pA[4];
    const unsigned short* ab = attb + ((size_t)(b * NH + h) * LL + ii) * LL + j0;
    #pragma unroll
    for (int kt = 0; kt < 4; ++kt)
        pA[kt] = *(const bf16x8*)&ab[kt * 32 + g * 8];

    // aE: B[k=j][n=c] = E[j][16w+lid] — lid 0..15 = one 64B sector, coalesced dwords
    const float* Eb = edge + ((size_t)bi * LL + j0) * DE + w * 16 + lid;
    f32x4 accE = (f32x4){0.f, 0.f, 0.f, 0.f};
    #pragma unroll
    for (int kt = 0; kt < 4; ++kt) {
        bf16x8 be;
        #pragma unroll
        for (int u = 0; u < 8; ++u)
            be[u] = (short)f2bf(Eb[(size_t)(kt * 32 + g * 8 + u) * DE]);
        accE = __builtin_amdgcn_mfma_f32_16x16x32_bf16(pA[kt], be, accE, 0, 0, 0);
    }

    // av: B[k=j][n=hd] = vT[hd][j0+k] — vector loads
    f32x4 accV[2];
    accV[0] = (f32x4){0.f, 0.f, 0.f, 0.f};
    accV[1] = (f32x4){0.f, 0.f, 0.f, 0.f};
    #pragma unroll
    for (int kt = 0; kt < 4; ++kt) {
        #pragma unroll
        for (int mt = 0; mt < 2; ++mt) {
            const bf16x8 vv = *(const bf16x8*)&vT[(size_t)(b * HD + w * DH + mt * 16 + lid) * LL + j0 + kt * 32 + g * 8];
            accV[mt] = __builtin_amdgcn_mfma_f32_16x16x32_bf16(pA[kt], vv, accV[mt], 0, 0, 0);
        }
    }

    // store partials: aE rows m=4g+r are h (valid m<8); av needs only h = hd>>5 = w
    float* aep = aEp + (size_t)(bi * 3 + jt) * (NH * DE);
    if (g < 2) {
        #pragma unroll
        for (int r = 0; r < 4; ++r)
            aep[(4 * g + r) * DE + w * 16 + lid] = accE[r];
    }
    float* avo = avp + (size_t)(bi * 3 + jt) * HD;
    #pragma unroll
    for (int mt = 0; mt < 2; ++mt)
        #pragma unroll
        for (int r = 0; r < 4; ++r)
            if (4 * g + r == w)
                avo[w * DH + mt * 16 + lid] = accV[mt][r];
}

// ---------------- finale: out = u + av + aE @ We_h ----------------
// grid = NB*LL blocks, 256 threads (thread = hd). One barrier.
__global__ __launch_bounds__(256) void finale_kernel(
    const float* __restrict__ aEp, const float* __restrict__ avp,
    const float* __restrict__ We,              // (DE, HD) fp32
    const float* __restrict__ ub,
    float* __restrict__ out)
{
    __shared__ float aEs[NH * DE];  // 4 KiB
    const int bi = blockIdx.x, t = threadIdx.x;

    #pragma unroll
    for (int q = 0; q < 4; ++q) {
        const int x = t + 256 * q;
        aEs[x] = aEp[(size_t)(bi * 3 + 0) * (NH * DE) + x]
               + aEp[(size_t)(bi * 3 + 1) * (NH * DE) + x]
               + aEp[(size_t)(bi * 3 + 2) * (NH * DE) + x];
    }
    __syncthreads();

    const int hd = t, h = hd >> 5;
    float acc = ub[(size_t)bi * HD + hd]
              + avp[(size_t)(bi * 3 + 0) * HD + hd]
              + avp[(size_t)(bi * 3 + 1) * HD + hd]
              + avp[(size_t)(bi * 3 + 2) * HD + hd];

    const float* sa = &aEs[h * DE];
    float a0 = 0.f, a1 = 0.f, a2 = 0.f, a3 = 0.f;
    #pragma unroll
    for (int c = 0; c < DE; c += 4) {
        a0 += sa[c]     * We[(size_t)(c)     * HD + hd];
        a1 += sa[c + 1] * We[(size_t)(c + 1) * HD + hd];
        a2 += sa[c + 2] * We[(size_t)(c + 2) * HD + hd];
        a3 += sa[c + 3] * We[(size_t)(c + 3) * HD + hd];
    }
    out[(size_t)bi * HD + hd] = acc + ((a0 + a1) + (a2 + a3));
}

extern "C" void kernel_launch(void* const* d_in, const int* in_sizes, int n_in,
                              void* d_out, int out_size, void* d_ws, size_t ws_size,
                              hipStream_t stream) {
    const float* node = (const float*)d_in[0];
    const float* edge = (const float*)d_in[1];
    const float* mask = (const float*)d_in[2];
    const float* Wq   = (const float*)d_in[3];
    const float* bq   = (const float*)d_in[4];
    const float* Wk   = (const float*)d_in[5];
    const float* bk   = (const float*)d_in[6];
    const float* Wv   = (const float*)d_in[7];
    const float* bv   = (const float*)d_in[8];
    const float* We   = (const float*)d_in[9];
    const float* Wu   = (const float*)d_in[10];
    const float* bu   = (const float*)d_in[11];
    float* out = (float*)d_out;

    const size_t rowsz = (size_t)NB * LL * HD;            // 196608
    const size_t lsz   = (size_t)NB * NH * LL * LL;       // 2359296
    float* ws   = (float*)d_ws;
    float* vb   = ws;
    float* ubuf = vb + rowsz;
    float* lpre = ubuf + rowsz;                           // lsz
    float* aEp  = lpre + lsz;                             // NB*LL*3*NH*DE = 2359296
    float* avp  = aEp + (size_t)NB * LL * 3 * NH * DE;    // NB*LL*3*HD = 589824
    unsigned short* us   = (unsigned short*)(avp + (size_t)NB * LL * 3 * HD);
    unsigned short* WeT  = us;                            // HD*DE = 32768
    unsigned short* qb16 = WeT + (size_t)HD * DE;
    unsigned short* kb16 = qb16 + rowsz;
    unsigned short* vT   = kb16 + rowsz;
    unsigned short* qWeB = vT + rowsz;                    // NB*LL*NH*DE = 786432
    unsigned short* attb = qWeB + (size_t)NB * LL * NH * DE; // lsz u16

    hipLaunchKernelGGL(prep_we, dim3(HD), dim3(DE), 0, stream, We, WeT);
    hipLaunchKernelGGL(proj_kernel, dim3(NB * LL / 4), dim3(256), 0, stream,
                       node, Wq, bq, Wk, bk, Wv, bv, Wu, bu, qb16, kb16, vb, ubuf);
    hipLaunchKernelGGL(vt_kernel, dim3(NB * (LL / 64) * (HD / 64)), dim3(256), 0, stream,
                       vb, vT);
    hipLaunchKernelGGL(qk_kernel, dim3(NB * NH * (LL / 64) * (LL / 64)), dim3(256), 0, stream,
                       qb16, kb16, mask, lpre);
    hipLaunchKernelGGL(qwe_kernel, dim3(NB * LL), dim3(256), 0, stream,
                       qb16, WeT, qWeB);
    hipLaunchKernelGGL(elog_kernel, dim3(NB * LL * 3), dim3(256), 0, stream,
                       edge, qWeB, lpre);
    hipLaunchKernelGGL(smax_kernel, dim3(NB * NH * LL / 4), dim3(256), 0, stream,
                       lpre, attb);
    hipLaunchKernelGGL(pvs_kernel, dim3(NB * LL * 3), dim3(512), 0, stream,
                       edge, attb, vT, aEp, avp);
    hipLaunchKernelGGL(finale_kernel, dim3(NB * LL), dim3(256), 0, stream,
                       aEp, avp, We, ubuf, out);
}

// Round 3
// 114.417 us; speedup vs baseline: 1.0658x; 1.0658x over previous
//
#include <hip/hip_runtime.h>
#include <cstdint>

#define NB 2
#define LL 384
#define DIN 256
#define DE 128
#define NH 8
#define DH 32
#define HD 256          // NH*DH
#define SCALE 0.17677669529663687f

typedef __attribute__((ext_vector_type(8))) short bf16x8;
typedef __attribute__((ext_vector_type(4))) float f32x4;

static __device__ __forceinline__ unsigned short f2bf(float f) {
    uint32_t u = __builtin_bit_cast(uint32_t, f);
    u += 0x7FFF + ((u >> 16) & 1);          // RNE
    return (unsigned short)(u >> 16);
}
static __device__ __forceinline__ float bf2f(unsigned short u) {
    return __builtin_bit_cast(float, (uint32_t)u << 16);
}
static __device__ __forceinline__ float getf4(const float4& v, int k) {
    return k == 0 ? v.x : k == 1 ? v.y : k == 2 ? v.z : v.w;
}
static __device__ __forceinline__ bf16x8 pack8(const float4& a, const float4& b) {
    bf16x8 p;
    p[0]=(short)f2bf(a.x); p[1]=(short)f2bf(a.y); p[2]=(short)f2bf(a.z); p[3]=(short)f2bf(a.w);
    p[4]=(short)f2bf(b.x); p[5]=(short)f2bf(b.y); p[6]=(short)f2bf(b.z); p[7]=(short)f2bf(b.w);
    return p;
}

// ---------------- prep_we: We^T -> bf16 (HD x DE, n-major) ----------------
__global__ __launch_bounds__(128) void prep_we(const float* __restrict__ We,
                                               unsigned short* __restrict__ WeT) {
    const int n = blockIdx.x;    // 0..255
    const int k = threadIdx.x;   // 0..127
    WeT[n * DE + k] = f2bf(We[(size_t)k * HD + n]);
}

// ---------------- proj: q/k -> bf16, v/u -> fp32 ----------------
__global__ __launch_bounds__(256) void proj_kernel(
    const float* __restrict__ node,
    const float* __restrict__ Wq, const float* __restrict__ bq,
    const float* __restrict__ Wk, const float* __restrict__ bk,
    const float* __restrict__ Wv, const float* __restrict__ bv,
    const float* __restrict__ Wu, const float* __restrict__ bu,
    unsigned short* __restrict__ qb16, unsigned short* __restrict__ kb16,
    float* __restrict__ vb, float* __restrict__ ub)
{
    __shared__ __align__(16) float rows[4][DIN];
    const int t  = threadIdx.x;
    const int r0 = blockIdx.x * 4;

    #pragma unroll
    for (int r = 0; r < 4; ++r)
        rows[r][t] = node[(size_t)(r0 + r) * DIN + t];
    __syncthreads();

    float aq[4], ak[4], av[4], au[4];
    {
        const float vq = bq[t], vk = bk[t], vv = bv[t], vu = bu[t];
        #pragma unroll
        for (int r = 0; r < 4; ++r) { aq[r] = vq; ak[r] = vk; av[r] = vv; au[r] = vu; }
    }

    for (int f4 = 0; f4 < DIN / 4; ++f4) {
        float4 xv[4];
        #pragma unroll
        for (int r = 0; r < 4; ++r)
            xv[r] = *(const float4*)&rows[r][f4 * 4];
        #pragma unroll
        for (int k = 0; k < 4; ++k) {
            const int f = f4 * 4 + k;
            const float wq = Wq[(size_t)f * HD + t];
            const float wk = Wk[(size_t)f * HD + t];
            const float wv = Wv[(size_t)f * HD + t];
            const float wu = Wu[(size_t)f * HD + t];
            #pragma unroll
            for (int r = 0; r < 4; ++r) {
                const float x = getf4(xv[r], k);
                aq[r] += x * wq; ak[r] += x * wk; av[r] += x * wv; au[r] += x * wu;
            }
        }
    }

    #pragma unroll
    for (int r = 0; r < 4; ++r) {
        const size_t o = (size_t)(r0 + r) * HD + t;
        qb16[o] = f2bf(aq[r]); kb16[o] = f2bf(ak[r]);
        vb[o] = av[r]; ub[o] = au[r];
    }
}

// ---------------- vt: v (fp32, j-major) -> vT (bf16, col-major) ----------------
__global__ __launch_bounds__(256) void vt_kernel(const float* __restrict__ vb,
                                                 unsigned short* __restrict__ vT) {
    __shared__ float tile[64][65];
    int blk = blockIdx.x;
    const int b  = blk / 24; blk %= 24;
    const int jt = blk / 4;
    const int ct = blk % 4;
    const int j0 = jt * 64, c0 = ct * 64;
    const int t  = threadIdx.x;
    const int c  = t & 63, j4 = t >> 6;
    #pragma unroll
    for (int rr = 0; rr < 16; ++rr) {
        const int j = j4 + 4 * rr;
        tile[j][c] = vb[(size_t)(b * LL + j0 + j) * HD + c0 + c];
    }
    __syncthreads();
    const int jj = t & 63, c4 = t >> 6;
    #pragma unroll
    for (int rr = 0; rr < 16; ++rr) {
        const int cc = c4 + 4 * rr;
        vT[(size_t)(b * HD + c0 + cc) * LL + j0 + jj] = f2bf(tile[jj][cc]);
    }
}

// ---------------- qk: lpre[b,h,i,j] = SCALE*(q.k) - 1e9*(1-mask) ----------------
__global__ __launch_bounds__(256) void qk_kernel(
    const unsigned short* __restrict__ qb16, const unsigned short* __restrict__ kb16,
    const float* __restrict__ mask, float* __restrict__ logit_pre)
{
    int idx = blockIdx.x;
    const int jt = idx % 6; idx /= 6;
    const int it = idx % 6; idx /= 6;
    const int h  = idx % NH;
    const int b  = idx / NH;
    const int t    = threadIdx.x;
    const int lane = t & 63;
    const int w    = t >> 6;
    const int lid  = lane & 15;
    const int g    = lane >> 4;
    const int i0 = it * 64 + w * 16;
    const int j0 = jt * 64;

    const bf16x8 afr = *(const bf16x8*)&qb16[(size_t)(b * LL + i0 + lid) * HD + h * DH + g * 8];
    f32x4 acc[4];
    #pragma unroll
    for (int jj = 0; jj < 4; ++jj) {
        const bf16x8 bfrg = *(const bf16x8*)&kb16[(size_t)(b * LL + j0 + jj * 16 + lid) * HD + h * DH + g * 8];
        acc[jj] = __builtin_amdgcn_mfma_f32_16x16x32_bf16(afr, bfrg, (f32x4){0.f,0.f,0.f,0.f}, 0, 0, 0);
    }
    #pragma unroll
    for (int jj = 0; jj < 4; ++jj) {
        #pragma unroll
        for (int r = 0; r < 4; ++r) {
            const int i = i0 + 4 * g + r;
            const int j = j0 + jj * 16 + lid;
            const float lg = SCALE * acc[jj][r]
                           + (1.0f - mask[(size_t)(b * LL + i) * LL + j]) * -1e9f;
            logit_pre[((size_t)(b * NH + h) * LL + i) * LL + j] = lg;
        }
    }
}

// ---------------- qwe: qWe[b,i,h,c] = SCALE * sum_d q[b,i,h*32+d]*We[c,h*32+d] ----------------
__global__ __launch_bounds__(256) void qwe_kernel(
    const unsigned short* __restrict__ qb16, const unsigned short* __restrict__ WeT,
    unsigned short* __restrict__ qWe)
{
    const int bi = blockIdx.x;
    const int t  = threadIdx.x;
    const int h  = t >> 5;
    const int c0 = (t & 31) * 4;

    float qv[32];
    const unsigned short* qp = &qb16[(size_t)bi * HD + h * DH];
    #pragma unroll
    for (int d = 0; d < 32; ++d) qv[d] = bf2f(qp[d]);

    float acc0 = 0.f, acc1 = 0.f, acc2 = 0.f, acc3 = 0.f;
    #pragma unroll
    for (int d = 0; d < 32; ++d) {
        const ushort4 wt = *(const ushort4*)&WeT[(size_t)(h * DH + d) * DE + c0];
        acc0 += qv[d] * bf2f(wt.x); acc1 += qv[d] * bf2f(wt.y);
        acc2 += qv[d] * bf2f(wt.z); acc3 += qv[d] * bf2f(wt.w);
    }
    unsigned short* o = &qWe[(size_t)bi * (NH * DE) + h * DE + c0];
    o[0] = f2bf(SCALE * acc0); o[1] = f2bf(SCALE * acc1);
    o[2] = f2bf(SCALE * acc2); o[3] = f2bf(SCALE * acc3);
}

// ---------------- fused: single edge pass; per-(b,i) block, 8 independent waves ----
// Wave w owns j in [48w, 48w+48). Per wave: logits (E@qWe + lpre) -> wave-local
// softmax -> p in wave-private LDS -> aE = p@E (E cols re-read, L1/L2-hot) and
// av = p@vT via MFMA. One barrier; in-LDS merge of 8 wave-partials; epilogue
// out = u + av + aE@We. No main-loop barriers, no global partials.
__global__ __launch_bounds__(512, 4) void fused_kernel(
    const float* __restrict__ edge,            // (B,L,L,DE) fp32
    const unsigned short* __restrict__ qWe,    // (B,L,NH,DE) bf16, SCALE folded
    const float* __restrict__ lpre,            // (B,NH,L,L) SCALE*qk+maskpen
    const unsigned short* __restrict__ vT,     // (B,HD,L) bf16 col-major
    const float* __restrict__ We,              // (DE,HD) fp32
    const float* __restrict__ ub,
    float* __restrict__ out)
{
    __shared__ __align__(16) unsigned short p_lds[8 * 8 * 64]; // 8 KiB: [w][h][j64] bf16
    __shared__ float aEw[8 * NH * DE];                         // 32 KiB: [w][h][c]
    __shared__ float avw[8 * HD];                              // 8 KiB: [w][hd]
    __shared__ float mlw[8][2][NH];                            // 512 B: [w][m|l][h]
    __shared__ float aEm[NH * DE];                             // 4 KiB merged

    const int t = threadIdx.x, lane = t & 63, w = t >> 6;
    const int lid = lane & 15, g = lane >> 4;
    const int bi = blockIdx.x, b = bi / LL, ii = bi % LL;
    const int j0w = w * 48;
    const int h8 = lid & 7;

    // --- qWe B-frags: B[k=c][n=h] ---
    bf16x8 qfr[4];
    {
        const unsigned short* qwp = &qWe[(size_t)bi * (NH * DE) + h8 * DE];
        #pragma unroll
        for (int kt = 0; kt < 4; ++kt)
            qfr[kt] = *(const bf16x8*)&qwp[kt * 32 + g * 8];
    }

    // --- logits: acc[mt] = E(48x128) @ qWe^T(128x16), A-frags straight from global ---
    f32x4 acc[3];
    #pragma unroll
    for (int mt = 0; mt < 3; ++mt) {
        acc[mt] = (f32x4){0.f, 0.f, 0.f, 0.f};
        const float* ef = edge + ((size_t)bi * LL + j0w + mt * 16 + lid) * DE;
        #pragma unroll
        for (int kt = 0; kt < 4; ++kt) {
            const float4 x0 = *(const float4*)&ef[kt * 32 + g * 8];
            const float4 x1 = *(const float4*)&ef[kt * 32 + g * 8 + 4];
            acc[mt] = __builtin_amdgcn_mfma_f32_16x16x32_bf16(pack8(x0, x1), qfr[kt], acc[mt], 0, 0, 0);
        }
    }

    // --- add qk logits; lanes lid>=8 poisoned (their cols are dup heads) ---
    const float* lrow = lpre + ((size_t)(b * NH + h8) * LL + ii) * LL;
    float lg[12];
    #pragma unroll
    for (int mt = 0; mt < 3; ++mt) {
        const float4 qk4 = *(const float4*)&lrow[j0w + mt * 16 + 4 * g];
        #pragma unroll
        for (int r = 0; r < 4; ++r)
            lg[mt * 4 + r] = (lid < 8) ? (acc[mt][r] + getf4(qk4, r)) : -3e38f;
    }

    // --- wave-local softmax over 48 j, per h (xor16/32 never mixes lids) ---
    float m = lg[0];
    #pragma unroll
    for (int k = 1; k < 12; ++k) m = fmaxf(m, lg[k]);
    m = fmaxf(m, __shfl_xor(m, 16));
    m = fmaxf(m, __shfl_xor(m, 32));
    float p[12], s = 0.f;
    #pragma unroll
    for (int k = 0; k < 12; ++k) { p[k] = __expf(lg[k] - m); s += p[k]; }
    s += __shfl_xor(s, 16); s += __shfl_xor(s, 32);
    if (lane < 8) { mlw[w][0][lane] = m; mlw[w][1][lane] = s; }

    // --- p -> wave-private LDS [h][j64] bf16; zero-pad j 48..63 ---
    unsigned short* pw = &p_lds[w * 512];
    if (lid < 8) {
        #pragma unroll
        for (int mt = 0; mt < 3; ++mt)
            #pragma unroll
            for (int r = 0; r < 4; ++r)
                pw[lid * 64 + mt * 16 + 4 * g + r] = f2bf(p[mt * 4 + r]);
    }
    ((unsigned int*)pw)[(lane >> 3) * 32 + 24 + (lane & 7)] = 0;

    // --- p A-frags: A[m=h][k=j] (rows 8..15 dup, outputs discarded) ---
    bf16x8 pA[2];
    #pragma unroll
    for (int kt = 0; kt < 2; ++kt)
        pA[kt] = *(const bf16x8*)&pw[h8 * 64 + kt * 32 + g * 8];

    // --- aE[h][c] = p @ E : B[k=j][n=c], E columns re-read (cache-hot), j clamped ---
    {
        float* aEp_w = &aEw[w * NH * DE];
        #pragma unroll
        for (int ct = 0; ct < 8; ++ct) {
            f32x4 aacc = (f32x4){0.f, 0.f, 0.f, 0.f};
            #pragma unroll
            for (int kt = 0; kt < 2; ++kt) {
                bf16x8 be;
                #pragma unroll
                for (int u = 0; u < 8; ++u) {
                    int jj = j0w + kt * 32 + g * 8 + u;
                    jj = jj > LL - 1 ? LL - 1 : jj;     // p=0 beyond slice
                    be[u] = (short)f2bf(edge[((size_t)bi * LL + jj) * DE + ct * 16 + lid]);
                }
                aacc = __builtin_amdgcn_mfma_f32_16x16x32_bf16(pA[kt], be, aacc, 0, 0, 0);
            }
            if (g < 2) {
                #pragma unroll
                for (int r = 0; r < 4; ++r)
                    aEp_w[(4 * g + r) * DE + ct * 16 + lid] = aacc[r];
            }
        }
    }

    // --- av[hd] = p @ vT : B[k=j][n=hd], vector loads ---
    {
        float* av_w = &avw[w * HD];
        const unsigned short* vTb = vT + (size_t)b * HD * LL;
        #pragma unroll
        for (int nt = 0; nt < 16; ++nt) {
            f32x4 vacc = (f32x4){0.f, 0.f, 0.f, 0.f};
            #pragma unroll
            for (int kt = 0; kt < 2; ++kt) {
                const bf16x8 vv = *(const bf16x8*)&vTb[(size_t)(nt * 16 + lid) * LL + j0w + kt * 32 + g * 8];
                vacc = __builtin_amdgcn_mfma_f32_16x16x32_bf16(pA[kt], vv, vacc, 0, 0, 0);
            }
            const int hn = nt >> 1;                      // head this hd-chunk belongs to
            if (g == (hn >> 2)) av_w[nt * 16 + lid] = vacc[hn & 3];
        }
    }

    __syncthreads();

    // --- merge aE across waves (normalized by L) ---
    #pragma unroll
    for (int q = 0; q < 2; ++q) {
        const int idx = t + q * 512;                     // 0..1023 = h*128+c
        const int h = idx >> 7, c = idx & 127;
        float M = mlw[0][0][h];
        #pragma unroll
        for (int w2 = 1; w2 < 8; ++w2) M = fmaxf(M, mlw[w2][0][h]);
        float L = 0.f, a = 0.f;
        #pragma unroll
        for (int w2 = 0; w2 < 8; ++w2) {
            const float f = __expf(mlw[w2][0][h] - M);
            L += f * mlw[w2][1][h];
            a += f * aEw[w2 * NH * DE + h * DE + c];
        }
        aEm[idx] = a / L;
    }
    __syncthreads();

    // --- merge av + epilogue: out = u + av + aE @ We_h ---
    if (t < HD) {
        const int hd = t, h = hd >> 5;
        float M = mlw[0][0][h];
        #pragma unroll
        for (int w2 = 1; w2 < 8; ++w2) M = fmaxf(M, mlw[w2][0][h]);
        float L = 0.f, avv = 0.f;
        #pragma unroll
        for (int w2 = 0; w2 < 8; ++w2) {
            const float f = __expf(mlw[w2][0][h] - M);
            L += f * mlw[w2][1][h];
            avv += f * avw[w2 * HD + hd];
        }
        float o = ub[(size_t)bi * HD + hd] + avv / L;
        const float* sa = &aEm[h * DE];
        float a0 = 0.f, a1 = 0.f, a2 = 0.f, a3 = 0.f;
        #pragma unroll
        for (int c = 0; c < DE; c += 4) {
            a0 += sa[c]     * We[(size_t)(c)     * HD + hd];
            a1 += sa[c + 1] * We[(size_t)(c + 1) * HD + hd];
            a2 += sa[c + 2] * We[(size_t)(c + 2) * HD + hd];
            a3 += sa[c + 3] * We[(size_t)(c + 3) * HD + hd];
        }
        out[(size_t)bi * HD + hd] = o + ((a0 + a1) + (a2 + a3));
    }
}

extern "C" void kernel_launch(void* const* d_in, const int* in_sizes, int n_in,
                              void* d_out, int out_size, void* d_ws, size_t ws_size,
                              hipStream_t stream) {
    const float* node = (const float*)d_in[0];
    const float* edge = (const float*)d_in[1];
    const float* mask = (const float*)d_in[2];
    const float* Wq   = (const float*)d_in[3];
    const float* bq   = (const float*)d_in[4];
    const float* Wk   = (const float*)d_in[5];
    const float* bk   = (const float*)d_in[6];
    const float* Wv   = (const float*)d_in[7];
    const float* bv   = (const float*)d_in[8];
    const float* We   = (const float*)d_in[9];
    const float* Wu   = (const float*)d_in[10];
    const float* bu   = (const float*)d_in[11];
    float* out = (float*)d_out;

    const size_t rowsz = (size_t)NB * LL * HD;            // 196608
    const size_t lsz   = (size_t)NB * NH * LL * LL;       // 2359296
    float* ws   = (float*)d_ws;
    float* vb   = ws;
    float* ubuf = vb + rowsz;
    float* lpre = ubuf + rowsz;                           // lsz
    unsigned short* us   = (unsigned short*)(lpre + lsz);
    unsigned short* WeT  = us;                            // HD*DE = 32768
    unsigned short* qb16 = WeT + (size_t)HD * DE;
    unsigned short* kb16 = qb16 + rowsz;
    unsigned short* vT   = kb16 + rowsz;
    unsigned short* qWeB = vT + rowsz;                    // NB*LL*NH*DE = 786432

    hipLaunchKernelGGL(prep_we, dim3(HD), dim3(DE), 0, stream, We, WeT);
    hipLaunchKernelGGL(proj_kernel, dim3(NB * LL / 4), dim3(256), 0, stream,
                       node, Wq, bq, Wk, bk, Wv, bv, Wu, bu, qb16, kb16, vb, ubuf);
    hipLaunchKernelGGL(vt_kernel, dim3(NB * (LL / 64) * (HD / 64)), dim3(256), 0, stream,
                       vb, vT);
    hipLaunchKernelGGL(qk_kernel, dim3(NB * NH * (LL / 64) * (LL / 64)), dim3(256), 0, stream,
                       qb16, kb16, mask, lpre);
    hipLaunchKernelGGL(qwe_kernel, dim3(NB * LL), dim3(256), 0, stream,
                       qb16, WeT, qWeB);
    hipLaunchKernelGGL(fused_kernel, dim3(NB * LL), dim3(512), 0, stream,
                       edge, qWeB, lpre, vT, We, ubuf, out);
}

// Round 4
// 109.482 us; speedup vs baseline: 1.1138x; 1.0451x over previous
//
#include <hip/hip_runtime.h>
#include <cstdint>

#define NB 2
#define LL 384
#define DIN 256
#define DE 128
#define NH 8
#define DH 32
#define HD 256          // NH*DH
#define SCALE 0.17677669529663687f
#define PBS 400         // pb row stride (u16) — padded vs 384 to spread banks

typedef __attribute__((ext_vector_type(8))) short bf16x8;
typedef __attribute__((ext_vector_type(4))) float f32x4;

static __device__ __forceinline__ unsigned short f2bf(float f) {
    uint32_t u = __builtin_bit_cast(uint32_t, f);
    u += 0x7FFF + ((u >> 16) & 1);          // RNE
    return (unsigned short)(u >> 16);
}
static __device__ __forceinline__ float bf2f(unsigned short u) {
    return __builtin_bit_cast(float, (uint32_t)u << 16);
}
static __device__ __forceinline__ float getf4(const float4& v, int k) {
    return k == 0 ? v.x : k == 1 ? v.y : k == 2 ? v.z : v.w;
}
static __device__ __forceinline__ bf16x8 pack8(const float4& a, const float4& b) {
    bf16x8 p;
    p[0]=(short)f2bf(a.x); p[1]=(short)f2bf(a.y); p[2]=(short)f2bf(a.z); p[3]=(short)f2bf(a.w);
    p[4]=(short)f2bf(b.x); p[5]=(short)f2bf(b.y); p[6]=(short)f2bf(b.z); p[7]=(short)f2bf(b.w);
    return p;
}

// ---------------- prep_we: We^T -> bf16 (HD x DE, n-major) ----------------
__global__ __launch_bounds__(128) void prep_we(const float* __restrict__ We,
                                               unsigned short* __restrict__ WeT) {
    const int n = blockIdx.x;    // 0..255
    const int k = threadIdx.x;   // 0..127
    WeT[n * DE + k] = f2bf(We[(size_t)k * HD + n]);
}

// ---------------- proj: q/k -> bf16, v/u -> fp32 ----------------
__global__ __launch_bounds__(256) void proj_kernel(
    const float* __restrict__ node,
    const float* __restrict__ Wq, const float* __restrict__ bq,
    const float* __restrict__ Wk, const float* __restrict__ bk,
    const float* __restrict__ Wv, const float* __restrict__ bv,
    const float* __restrict__ Wu, const float* __restrict__ bu,
    unsigned short* __restrict__ qb16, unsigned short* __restrict__ kb16,
    float* __restrict__ vb, float* __restrict__ ub)
{
    __shared__ __align__(16) float rows[4][DIN];
    const int t  = threadIdx.x;
    const int r0 = blockIdx.x * 4;

    #pragma unroll
    for (int r = 0; r < 4; ++r)
        rows[r][t] = node[(size_t)(r0 + r) * DIN + t];
    __syncthreads();

    float aq[4], ak[4], av[4], au[4];
    {
        const float vq = bq[t], vk = bk[t], vv = bv[t], vu = bu[t];
        #pragma unroll
        for (int r = 0; r < 4; ++r) { aq[r] = vq; ak[r] = vk; av[r] = vv; au[r] = vu; }
    }

    for (int f4 = 0; f4 < DIN / 4; ++f4) {
        float4 xv[4];
        #pragma unroll
        for (int r = 0; r < 4; ++r)
            xv[r] = *(const float4*)&rows[r][f4 * 4];
        #pragma unroll
        for (int k = 0; k < 4; ++k) {
            const int f = f4 * 4 + k;
            const float wq = Wq[(size_t)f * HD + t];
            const float wk = Wk[(size_t)f * HD + t];
            const float wv = Wv[(size_t)f * HD + t];
            const float wu = Wu[(size_t)f * HD + t];
            #pragma unroll
            for (int r = 0; r < 4; ++r) {
                const float x = getf4(xv[r], k);
                aq[r] += x * wq; ak[r] += x * wk; av[r] += x * wv; au[r] += x * wu;
            }
        }
    }

    #pragma unroll
    for (int r = 0; r < 4; ++r) {
        const size_t o = (size_t)(r0 + r) * HD + t;
        qb16[o] = f2bf(aq[r]); kb16[o] = f2bf(ak[r]);
        vb[o] = av[r]; ub[o] = au[r];
    }
}

// ---------------- vt: v (fp32, j-major) -> vT (bf16, col-major) ----------------
__global__ __launch_bounds__(256) void vt_kernel(const float* __restrict__ vb,
                                                 unsigned short* __restrict__ vT) {
    __shared__ float tile[64][65];
    int blk = blockIdx.x;
    const int b  = blk / 24; blk %= 24;
    const int jt = blk / 4;
    const int ct = blk % 4;
    const int j0 = jt * 64, c0 = ct * 64;
    const int t  = threadIdx.x;
    const int c  = t & 63, j4 = t >> 6;
    #pragma unroll
    for (int rr = 0; rr < 16; ++rr) {
        const int j = j4 + 4 * rr;
        tile[j][c] = vb[(size_t)(b * LL + j0 + j) * HD + c0 + c];
    }
    __syncthreads();
    const int jj = t & 63, c4 = t >> 6;
    #pragma unroll
    for (int rr = 0; rr < 16; ++rr) {
        const int cc = c4 + 4 * rr;
        vT[(size_t)(b * HD + c0 + cc) * LL + j0 + jj] = f2bf(tile[jj][cc]);
    }
}

// ---------------- qk: lpre[b,h,i,j] = SCALE*(q.k) - 1e9*(1-mask) ----------------
__global__ __launch_bounds__(256) void qk_kernel(
    const unsigned short* __restrict__ qb16, const unsigned short* __restrict__ kb16,
    const float* __restrict__ mask, float* __restrict__ logit_pre)
{
    int idx = blockIdx.x;
    const int jt = idx % 6; idx /= 6;
    const int it = idx % 6; idx /= 6;
    const int h  = idx % NH;
    const int b  = idx / NH;
    const int t    = threadIdx.x;
    const int lane = t & 63;
    const int w    = t >> 6;
    const int lid  = lane & 15;
    const int g    = lane >> 4;
    const int i0 = it * 64 + w * 16;
    const int j0 = jt * 64;

    const bf16x8 afr = *(const bf16x8*)&qb16[(size_t)(b * LL + i0 + lid) * HD + h * DH + g * 8];
    f32x4 acc[4];
    #pragma unroll
    for (int jj = 0; jj < 4; ++jj) {
        const bf16x8 bfrg = *(const bf16x8*)&kb16[(size_t)(b * LL + j0 + jj * 16 + lid) * HD + h * DH + g * 8];
        acc[jj] = __builtin_amdgcn_mfma_f32_16x16x32_bf16(afr, bfrg, (f32x4){0.f,0.f,0.f,0.f}, 0, 0, 0);
    }
    #pragma unroll
    for (int jj = 0; jj < 4; ++jj) {
        #pragma unroll
        for (int r = 0; r < 4; ++r) {
            const int i = i0 + 4 * g + r;
            const int j = j0 + jj * 16 + lid;
            const float lg = SCALE * acc[jj][r]
                           + (1.0f - mask[(size_t)(b * LL + i) * LL + j]) * -1e9f;
            logit_pre[((size_t)(b * NH + h) * LL + i) * LL + j] = lg;
        }
    }
}

// ---------------- qwe: qWe[b,i,h,c] = SCALE * sum_d q[b,i,h*32+d]*We[c,h*32+d] ----------------
__global__ __launch_bounds__(256) void qwe_kernel(
    const unsigned short* __restrict__ qb16, const unsigned short* __restrict__ WeT,
    unsigned short* __restrict__ qWe)
{
    const int bi = blockIdx.x;
    const int t  = threadIdx.x;
    const int h  = t >> 5;
    const int c0 = (t & 31) * 4;

    float qv[32];
    const unsigned short* qp = &qb16[(size_t)bi * HD + h * DH];
    #pragma unroll
    for (int d = 0; d < 32; ++d) qv[d] = bf2f(qp[d]);

    float acc0 = 0.f, acc1 = 0.f, acc2 = 0.f, acc3 = 0.f;
    #pragma unroll
    for (int d = 0; d < 32; ++d) {
        const ushort4 wt = *(const ushort4*)&WeT[(size_t)(h * DH + d) * DE + c0];
        acc0 += qv[d] * bf2f(wt.x); acc1 += qv[d] * bf2f(wt.y);
        acc2 += qv[d] * bf2f(wt.z); acc3 += qv[d] * bf2f(wt.w);
    }
    unsigned short* o = &qWe[(size_t)bi * (NH * DE) + h * DE + c0];
    o[0] = f2bf(SCALE * acc0); o[1] = f2bf(SCALE * acc1);
    o[2] = f2bf(SCALE * acc2); o[3] = f2bf(SCALE * acc3);
}

// ---------------- fused2: single edge pass, LDS-staged E, block softmax ----
// grid = NB*LL (one block per (b,i)), 512 threads = 8 waves.
// Phase A: wave w, j-slice [48w,48w+48): hoisted edge loads -> pack -> logits
//   MFMA (E@qWe^T) + ds_write E tile (swizzled) to block-shared Es; wave-local
//   softmax (m,s) -> mlw.
// Barrier 1: global M,L per head; waves rescale in-register p -> normalized
//   bf16 p in pb LDS.  Barrier 2.
// Phase B: aE[h][c] (wave = 16-col slice, B-frags from swizzled Es) and
//   av[hd] (wave = head, vT from global L2) over all 384 j. Direct writes.
// Barrier 3: epilogue out = u + av + aE@We.
__global__ __launch_bounds__(512, 1) void fused2_kernel(
    const float* __restrict__ edge,            // (B,L,L,DE) fp32
    const unsigned short* __restrict__ qWe,    // (B,L,NH,DE) bf16, SCALE folded
    const float* __restrict__ lpre,            // (B,NH,L,L) SCALE*qk+maskpen
    const unsigned short* __restrict__ vT,     // (B,HD,L) bf16 col-major
    const float* __restrict__ We,              // (DE,HD) fp32
    const float* __restrict__ ub,
    float* __restrict__ out)
{
    __shared__ __align__(16) unsigned short Es[LL * DE];   // 96 KiB, swizzled bf16
    __shared__ __align__(16) unsigned short pb[NH * PBS];  // 6.25 KiB normalized p
    __shared__ float mlw[8][2][NH];                        // 512 B
    __shared__ float aEm[NH * DE];                         // 4 KiB
    __shared__ float avs[HD];                              // 1 KiB

    const int t = threadIdx.x, lane = t & 63, w = t >> 6;
    const int lid = lane & 15, g = lane >> 4;
    const int bi = blockIdx.x, b = bi / LL, ii = bi % LL;
    const int j0w = w * 48;
    const int h8 = lid & 7;

    // ---- Phase A: hoisted edge loads (24 float4 in flight) ----
    float4 eL[3][4][2];
    #pragma unroll
    for (int mt = 0; mt < 3; ++mt) {
        const float* ef = edge + ((size_t)bi * LL + j0w + mt * 16 + lid) * DE;
        #pragma unroll
        for (int kt = 0; kt < 4; ++kt) {
            eL[mt][kt][0] = *(const float4*)&ef[kt * 32 + g * 8];
            eL[mt][kt][1] = *(const float4*)&ef[kt * 32 + g * 8 + 4];
        }
    }
    float4 qk4[3];
    const float* lrow = lpre + ((size_t)(b * NH + h8) * LL + ii) * LL;
    #pragma unroll
    for (int mt = 0; mt < 3; ++mt)
        qk4[mt] = *(const float4*)&lrow[j0w + mt * 16 + 4 * g];

    bf16x8 qfr[4];
    {
        const unsigned short* qwp = &qWe[(size_t)bi * (NH * DE) + h8 * DE];
        #pragma unroll
        for (int kt = 0; kt < 4; ++kt)
            qfr[kt] = *(const bf16x8*)&qwp[kt * 32 + g * 8];
    }

    // pack + logits MFMA + stage E tile into LDS (swizzled: slot = chunk ^ (j&15))
    f32x4 acc[3];
    #pragma unroll
    for (int mt = 0; mt < 3; ++mt) {
        acc[mt] = (f32x4){0.f, 0.f, 0.f, 0.f};
        const int j = j0w + mt * 16 + lid;
        #pragma unroll
        for (int kt = 0; kt < 4; ++kt) {
            const bf16x8 pk = pack8(eL[mt][kt][0], eL[mt][kt][1]);
            *(bf16x8*)&Es[j * DE + (((kt * 4 + g) ^ (j & 15)) << 3)] = pk;
            acc[mt] = __builtin_amdgcn_mfma_f32_16x16x32_bf16(pk, qfr[kt], acc[mt], 0, 0, 0);
        }
    }

    // logits + wave-local softmax (per h; xor16/32 never mixes lids)
    float lg[12];
    #pragma unroll
    for (int mt = 0; mt < 3; ++mt)
        #pragma unroll
        for (int r = 0; r < 4; ++r)
            lg[mt * 4 + r] = (lid < 8) ? (acc[mt][r] + getf4(qk4[mt], r)) : -3e38f;

    float m = lg[0];
    #pragma unroll
    for (int k = 1; k < 12; ++k) m = fmaxf(m, lg[k]);
    m = fmaxf(m, __shfl_xor(m, 16));
    m = fmaxf(m, __shfl_xor(m, 32));
    float p[12], s = 0.f;
    #pragma unroll
    for (int k = 0; k < 12; ++k) { p[k] = __expf(lg[k] - m); s += p[k]; }
    s += __shfl_xor(s, 16); s += __shfl_xor(s, 32);
    if (lane < 8) { mlw[w][0][lane] = m; mlw[w][1][lane] = s; }

    __syncthreads();   // barrier 1: mlw ready (Es also done)

    // global M, L for this lane's head; rescale in-register p -> normalized
    {
        float M = mlw[0][0][h8];
        #pragma unroll
        for (int w2 = 1; w2 < 8; ++w2) M = fmaxf(M, mlw[w2][0][h8]);
        float Lsum = 0.f;
        #pragma unroll
        for (int w2 = 0; w2 < 8; ++w2)
            Lsum += __expf(mlw[w2][0][h8] - M) * mlw[w2][1][h8];
        const float f = __expf(m - M) / Lsum;
        if (lid < 8) {
            #pragma unroll
            for (int mt = 0; mt < 3; ++mt)
                #pragma unroll
                for (int r = 0; r < 4; ++r)
                    pb[h8 * PBS + j0w + mt * 16 + 4 * g + r] = f2bf(p[mt * 4 + r] * f);
        }
    }

    __syncthreads();   // barrier 2: pb (and Es) visible to all

    // ---- Phase B ----
    // p A-frags: A[m=h][k=j], rows 8..15 dup (outputs discarded)
    bf16x8 pA[12];
    #pragma unroll
    for (int kt = 0; kt < 12; ++kt)
        pA[kt] = *(const bf16x8*)&pb[h8 * PBS + kt * 32 + g * 8];

    // aE[h][c]: wave w owns c-slice [16w,16w+16); B-frags from swizzled Es
    {
        const int cE = 16 * w + lid, chE = cE >> 3, ceE = cE & 7;
        f32x4 accE = (f32x4){0.f, 0.f, 0.f, 0.f};
        #pragma unroll
        for (int kt = 0; kt < 12; ++kt) {
            bf16x8 be;
            #pragma unroll
            for (int u = 0; u < 8; ++u) {
                const int k = kt * 32 + g * 8 + u;
                be[u] = (short)Es[k * DE + ((chE ^ (k & 15)) << 3) + ceE];
            }
            accE = __builtin_amdgcn_mfma_f32_16x16x32_bf16(pA[kt], be, accE, 0, 0, 0);
        }
        if (g < 2) {
            #pragma unroll
            for (int r = 0; r < 4; ++r)
                aEm[(4 * g + r) * DE + cE] = accE[r];
        }
    }

    // av[hd]: wave w owns hd [32w,32w+32) (= head w); vT from global (L2-hot)
    {
        const unsigned short* vTb = vT + (size_t)b * HD * LL;
        #pragma unroll
        for (int mm = 0; mm < 2; ++mm) {
            const int hd = (2 * w + mm) * 16 + lid;
            const unsigned short* vr = &vTb[(size_t)hd * LL];
            f32x4 accV = (f32x4){0.f, 0.f, 0.f, 0.f};
            #pragma unroll
            for (int kt = 0; kt < 12; ++kt) {
                const bf16x8 vv = *(const bf16x8*)&vr[kt * 32 + g * 8];
                accV = __builtin_amdgcn_mfma_f32_16x16x32_bf16(pA[kt], vv, accV, 0, 0, 0);
            }
            if ((w >> 2) == g) {
                const int r = w & 3;
                const float val = r == 0 ? accV[0] : r == 1 ? accV[1] : r == 2 ? accV[2] : accV[3];
                avs[hd] = val;
            }
        }
    }

    __syncthreads();   // barrier 3

    // ---- epilogue: out = u + av + aE @ We_h (aE, av already /L normalized) ----
    if (t < HD) {
        const int hd = t, h = hd >> 5;
        float o = ub[(size_t)bi * HD + hd] + avs[hd];
        const float* sa = &aEm[h * DE];
        float a0 = 0.f, a1 = 0.f, a2 = 0.f, a3 = 0.f;
        #pragma unroll
        for (int c = 0; c < DE; c += 4) {
            a0 += sa[c]     * We[(size_t)(c)     * HD + hd];
            a1 += sa[c + 1] * We[(size_t)(c + 1) * HD + hd];
            a2 += sa[c + 2] * We[(size_t)(c + 2) * HD + hd];
            a3 += sa[c + 3] * We[(size_t)(c + 3) * HD + hd];
        }
        out[(size_t)bi * HD + hd] = o + ((a0 + a1) + (a2 + a3));
    }
}

extern "C" void kernel_launch(void* const* d_in, const int* in_sizes, int n_in,
                              void* d_out, int out_size, void* d_ws, size_t ws_size,
                              hipStream_t stream) {
    const float* node = (const float*)d_in[0];
    const float* edge = (const float*)d_in[1];
    const float* mask = (const float*)d_in[2];
    const float* Wq   = (const float*)d_in[3];
    const float* bq   = (const float*)d_in[4];
    const float* Wk   = (const float*)d_in[5];
    const float* bk   = (const float*)d_in[6];
    const float* Wv   = (const float*)d_in[7];
    const float* bv   = (const float*)d_in[8];
    const float* We   = (const float*)d_in[9];
    const float* Wu   = (const float*)d_in[10];
    const float* bu   = (const float*)d_in[11];
    float* out = (float*)d_out;

    const size_t rowsz = (size_t)NB * LL * HD;            // 196608
    const size_t lsz   = (size_t)NB * NH * LL * LL;       // 2359296
    float* ws   = (float*)d_ws;
    float* vb   = ws;
    float* ubuf = vb + rowsz;
    float* lpre = ubuf + rowsz;                           // lsz
    unsigned short* us   = (unsigned short*)(lpre + lsz);
    unsigned short* WeT  = us;                            // HD*DE = 32768
    unsigned short* qb16 = WeT + (size_t)HD * DE;
    unsigned short* kb16 = qb16 + rowsz;
    unsigned short* vT   = kb16 + rowsz;
    unsigned short* qWeB = vT + rowsz;                    // NB*LL*NH*DE = 786432

    hipLaunchKernelGGL(prep_we, dim3(HD), dim3(DE), 0, stream, We, WeT);
    hipLaunchKernelGGL(proj_kernel, dim3(NB * LL / 4), dim3(256), 0, stream,
                       node, Wq, bq, Wk, bk, Wv, bv, Wu, bu, qb16, kb16, vb, ubuf);
    hipLaunchKernelGGL(vt_kernel, dim3(NB * (LL / 64) * (HD / 64)), dim3(256), 0, stream,
                       vb, vT);
    hipLaunchKernelGGL(qk_kernel, dim3(NB * NH * (LL / 64) * (LL / 64)), dim3(256), 0, stream,
                       qb16, kb16, mask, lpre);
    hipLaunchKernelGGL(qwe_kernel, dim3(NB * LL), dim3(256), 0, stream,
                       qb16, WeT, qWeB);
    hipLaunchKernelGGL(fused2_kernel, dim3(NB * LL), dim3(512), 0, stream,
                       edge, qWeB, lpre, vT, We, ubuf, out);
}